// Round 7
// baseline (124.196 us; speedup 1.0000x reference)
//
#include <hip/hip_runtime.h>
#include <stdint.h>

typedef unsigned long long u64;
typedef unsigned int u32;

#define KCAND 9
#define BATCH 16
#define NPRED 30000
#define NGT   64
#define NPTS  (BATCH * NPRED)      // 480000
#define NCELL 1024                 // 32x32 grid
#define CDIM  32
#define CELLW (1.0f / 32.0f)
#define SENT  (~0ULL)
#define FINF  __uint_as_float(0x7F800000u)

__device__ __forceinline__ u64 wave_min_u64(u64 v) {
#pragma unroll
    for (int s = 1; s < 64; s <<= 1) {
        u64 o = __shfl_xor(v, s, 64);
        v = o < v ? o : v;
    }
    return v;
}
__device__ __forceinline__ float wave_min_f(float v) {
#pragma unroll
    for (int s = 1; s < 64; s <<= 1) v = fminf(v, __shfl_xor(v, s, 64));
    return v;
}
__device__ __forceinline__ u32 wave_iscan_u32(u32 v, int lane) {
#pragma unroll
    for (int s = 1; s < 64; s <<= 1) {
        u32 t = __shfl_up(v, s, 64);
        if (lane >= s) v += t;
    }
    return v;
}

// exact reference-rounded dist^2 (all ordering comes from this, contract-off)
#define DIST(GX, GY, PX, PY, D)                                              \
    { float _dx = __fsub_rn(GX, PX), _dy = __fsub_rn(GY, PY);                \
      D = __fadd_rn(__fmul_rn(_dx, _dx), __fmul_rn(_dy, _dy)); }

// merge per-lane batch keys bk into sorted top-9 (val lanes 0..8, SENT pads).
// keys are unique (idx embedded) -> at most one holder per selected min.
__device__ __forceinline__ u64 merge9(u64 val, u64 bk, int lane) {
    u64 a = (lane < KCAND) ? val : SENT;
    u64 nv = SENT;
#pragma unroll
    for (int r = 0; r < KCAND; ++r) {
        u64 ml = a < bk ? a : bk;
        u64 m = wave_min_u64(ml);
        if (lane == r) nv = m;
        if (a == m) a = SENT;
        else if (bk == m) bk = SENT;
    }
    return nv;
}

__device__ __forceinline__ int cell_of(float x, float y) {
    int cx = (int)(x * 32.0f); cx = cx < 0 ? 0 : (cx > 31 ? 31 : cx);
    int cy = (int)(y * 32.0f); cy = cy < 0 ? 0 : (cy > 31 ? 31 : cy);
    return (cy << 5) | cx;
}

// IoU + adaptive threshold + outputs; per-wave, lane r holds r-th best key.
__device__ void atss_epilogue(u64 fin, int b, int g, const float4* p4,
                              float4 gq, float* __restrict__ out, int lane) {
#pragma clang fp contract(off)
    const int w = b * NGT + g;
    const float gcx = gq.x, gcy = gq.y;
    const bool active = (lane < KCAND);
    const unsigned idx = active ? (unsigned)(fin & 0xffffffffu) : 0u;

    float4 pbx = p4[idx];

    float gx1 = gcx - 0.5f * gq.z, gy1 = gcy - 0.5f * gq.w;
    float gx2 = gcx + 0.5f * gq.z, gy2 = gcy + 0.5f * gq.w;
    float kx1 = pbx.x - 0.5f * pbx.z, ky1 = pbx.y - 0.5f * pbx.w;
    float kx2 = pbx.x + 0.5f * pbx.z, ky2 = pbx.y + 0.5f * pbx.w;

    float ltx = fmaxf(gx1, kx1), lty = fmaxf(gy1, ky1);
    float rbx = fminf(gx2, kx2), rby = fminf(gy2, ky2);
    float wvd = fmaxf(rbx - ltx, 0.0f);
    float hvd = fmaxf(rby - lty, 0.0f);
    float inter  = wvd * hvd;
    float area_a = (gx2 - gx1) * (gy2 - gy1);
    float area_b = (kx2 - kx1) * (ky2 - ky1);
    float iou = inter / ((area_a + area_b) - inter);

    float v = active ? iou : 0.0f;
    float s = v;
#pragma unroll
    for (int m = 1; m < 64; m <<= 1) s += __shfl_xor(s, m, 64);
    float mean = s / 9.0f;

    float dev = active ? (iou - mean) : 0.0f;
    float ss = dev * dev;
#pragma unroll
    for (int m = 1; m < 64; m <<= 1) ss += __shfl_xor(ss, m, 64);
    float stdv = sqrtf(ss / 8.0f);    // ddof = 1
    float thr = mean + stdv;

    bool inside = (gx1 <= pbx.x) && (pbx.x <= gx2) &&
                  (gy1 <= pbx.y) && (pbx.y <= gy2);
    bool maskk = (iou >= thr) && inside;

    if (active) {
        const size_t chunk = (size_t)BATCH * NGT * KCAND;   // 9216
        const size_t o = (size_t)w * KCAND + lane;
        out[0 * chunk + o] = maskk ? (float)idx : -1.0f;    // pred_idx
        out[1 * chunk + o] = maskk ? (float)g   : -1.0f;    // gt_idx
        out[2 * chunk + o] = maskk ? 1.0f : 0.0f;           // mask
        out[3 * chunk + o] = iou;                           // ious
    }
}

// ===== stage 1: zero the cell counters (ws arrives poisoned) ================
__global__ __launch_bounds__(256) void zero_meta(u32* __restrict__ mcount) {
    int i = blockIdx.x * 256 + threadIdx.x;
    if (i < BATCH * NCELL) mcount[i] = 0;
}

// ===== stage 2: wide histogram — one thread per point, global atomics =======
// per-image counter array is 4 KB (L2-resident); ~30 adds/cell -> low contention
__global__ __launch_bounds__(256) void hist(
    const float* __restrict__ pred, u32* __restrict__ mcount)
{
    int e = blockIdx.x * 256 + threadIdx.x;
    if (e >= NPTS) return;
    float4 q = ((const float4*)pred)[e];
    int b = e / NPRED;
    atomicAdd(&mcount[b * NCELL + cell_of(q.x, q.y)], 1u);
}

// ===== stage 3: per-image prefix over 1024 cells (round-6-proven scan) ======
__global__ __launch_bounds__(512) void prefix(
    const u32* __restrict__ mcount, u32* __restrict__ mstart,
    u32* __restrict__ cur)
{
    const int b    = blockIdx.x;
    const int tid  = threadIdx.x;
    const int lane = tid & 63;
    const int wv   = tid >> 6;

    __shared__ u32 wtot[8];
    const int c0 = (wv << 7) + lane, c1 = c0 + 64;   // wave w: cells [128w,128w+128)
    u32 a0 = mcount[b * NCELL + c0], a1 = mcount[b * NCELL + c1];
    u32 s0 = wave_iscan_u32(a0, lane);
    u32 t0 = __shfl(s0, 63, 64);
    u32 s1 = wave_iscan_u32(a1, lane) + t0;
    if (lane == 63) wtot[wv] = s1;
    __syncthreads();
    u32 off = 0;
    for (int k = 0; k < wv; ++k) off += wtot[k];
    const u32 st0 = off + s0 - a0, st1 = off + s1 - a1;   // exclusive starts
    mstart[b * NCELL + c0] = st0;  mstart[b * NCELL + c1] = st1;
    cur[b * NCELL + c0]    = st0;  cur[b * NCELL + c1]    = st1;
}

// ===== stage 4: wide scatter — one thread per point =========================
// within-cell order nondeterministic (atomic) — harmless: selection is
// set-based on exact (d2,idx) keys (harness-proven in round 6).
__global__ __launch_bounds__(256) void scatter(
    const float* __restrict__ pred, u32* __restrict__ cur,
    float4* __restrict__ scat)
{
    int e = blockIdx.x * 256 + threadIdx.x;
    if (e >= NPTS) return;
    float4 q = ((const float4*)pred)[e];
    int b = e / NPRED;
    int i = e - b * NPRED;
    u32 slot = atomicAdd(&cur[b * NCELL + cell_of(q.x, q.y)], 1u);
    scat[(size_t)b * NPRED + slot] =
        make_float4(q.x, q.y, __uint_as_float((u32)i), 0.0f);
}

// ===== stage 5: per-GT expanding-ring exact top-9 + epilogue (UNCHANGED) ====
// 1024 one-wave blocks. b = bi&15 -> image b always lands on XCD b&7, so each
// XCD serves 2 images (~1 MB scat) from its own L2.
// Ring bound: after finishing rings 0..m, every unexamined point is in a cell
// with Chebyshev distance >= m+1, hence Euclidean distance > m*CELLW.
__global__ __launch_bounds__(64) void atss_search(
    const float4* __restrict__ scat, const u32* __restrict__ mstart,
    const u32* __restrict__ mcount,  const float* __restrict__ pred,
    const float* __restrict__ gt,    float* __restrict__ out)
{
#pragma clang fp contract(off)
    const int bi   = blockIdx.x;
    const int lane = threadIdx.x;
    const int b    = bi & 15;
    const int g    = bi >> 4;

    const float4 gq = ((const float4*)gt)[b * NGT + g];
    const float gx = gq.x, gy = gq.y;
    int cx = (int)(gx * 32.0f); cx = cx < 0 ? 0 : (cx > 31 ? 31 : cx);
    int cy = (int)(gy * 32.0f); cy = cy < 0 ? 0 : (cy > 31 ? 31 : cy);

    const float4* sb  = scat + (size_t)b * NPRED;
    const u32*    msb = mstart + b * NCELL;
    const u32*    mcb = mcount + b * NCELL;

    u64 val = SENT;                        // sorted top-9 in lanes 0..8

#define PCELL(CX, CY)                                                        \
    { const int _cc = ((CY) << 5) | (CX);                                    \
      const u32 _st = msb[_cc], _cn = mcb[_cc];                              \
      for (u32 _off = 0; _off < _cn; _off += 64) {                           \
          u64 bk = SENT;                                                     \
          const u32 _ii = _off + (u32)lane;                                  \
          if (_ii < _cn) {                                                   \
              float4 q = sb[_st + _ii];                                      \
              float dd; DIST(gx, gy, q.x, q.y, dd);                          \
              bk = ((u64)__float_as_uint(dd) << 32)                         \
                   | (u64)(u32)__float_as_uint(q.z);                         \
          }                                                                  \
          u64 bmin = wave_min_u64(bk);                                       \
          u64 k8s  = __shfl(val, 8, 64);                                     \
          if (bmin < k8s) val = merge9(val, bk, lane);                       \
      } }

    for (int m = 0;; ++m) {
        if (m == 0) {
            PCELL(cx, cy)
        } else {
            const int x0 = cx - m, x1 = cx + m, y0 = cy - m, y1 = cy + m;
            const int xa = x0 < 0 ? 0 : x0, xb = x1 > 31 ? 31 : x1;
            if (y0 >= 0) { for (int x = xa; x <= xb; ++x) PCELL(x, y0) }
            if (y1 <= 31){ for (int x = xa; x <= xb; ++x) PCELL(x, y1) }
            const int ya = (y0 + 1) < 0 ? 0 : (y0 + 1);
            const int yb = (y1 - 1) > 31 ? 31 : (y1 - 1);
            if (x0 >= 0) { for (int y = ya; y <= yb; ++y) PCELL(x0, y) }
            if (x1 <= 31){ for (int y = ya; y <= yb; ++y) PCELL(x1, y) }
        }
        const u64 k8 = __shfl(val, 8, 64);
        if (k8 != SENT) {
            const float d9f = __uint_as_float((u32)(k8 >> 32));
            float bd = (float)m * CELLW;
            const float bd2 = bd * bd * (1.0f - 1e-5f);   // conservative fp margin
            if (d9f < bd2) break;          // strict: no unexamined point can tie
        }
        if (m >= 31) break;                // all cells examined -> exact
    }
#undef PCELL

    atss_epilogue(val, b, g, (const float4*)pred + (size_t)b * NPRED,
                  gq, out, lane);
}

// ===== fallback (no workspace; correctness-only): per-wave 2-pass scan ======
__global__ __launch_bounds__(64) void atss_fullscan(
    const float* __restrict__ pred, const float* __restrict__ gt,
    float* __restrict__ out)
{
#pragma clang fp contract(off)
    const int bi   = blockIdx.x;
    const int lane = threadIdx.x;
    const int b    = bi & 15;
    const int g    = bi >> 4;

    const float4 gq = ((const float4*)gt)[b * NGT + g];
    const float gx = gq.x, gy = gq.y;
    const float4* p4 = (const float4*)pred + (size_t)b * NPRED;

    float lm = FINF;
    for (int i = lane; i < NPRED; i += 64) {
        float4 q = p4[i];
        float d; DIST(gx, gy, q.x, q.y, d);
        lm = fminf(lm, d);
    }
    // T = 9th-smallest lane-min: <=8 points < d9 => <=8 lane-mins < d9 => T>=d9
    float vv = lm, T = FINF;
#pragma unroll
    for (int r = 0; r < KCAND; ++r) {
        float m = wave_min_f(vv);
        T = m;
        u64 e = __ballot(vv == m);
        if (lane == __ffsll(e) - 1) vv = FINF;
    }

    u64 val = SENT;
    for (int i0 = 0; i0 < NPRED; i0 += 64) {
        const int i = i0 + lane;
        u64 bk = SENT;
        if (i < NPRED) {
            float4 q = p4[i];
            float d; DIST(gx, gy, q.x, q.y, d);
            if (d <= T) bk = ((u64)__float_as_uint(d) << 32) | (u32)i;
        }
        if (__ballot(bk != SENT)) {
            u64 bmin = wave_min_u64(bk);
            u64 k8s  = __shfl(val, 8, 64);
            if (bmin < k8s) val = merge9(val, bk, lane);
        }
    }
    atss_epilogue(val, b, g, p4, gq, out, lane);
}

extern "C" void kernel_launch(void* const* d_in, const int* in_sizes, int n_in,
                              void* d_out, int out_size, void* d_ws, size_t ws_size,
                              hipStream_t stream) {
    const float* pred = (const float*)d_in[0];   // [16, 30000, 4] f32
    const float* gtb  = (const float*)d_in[1];   // [16, 64, 4] f32
    float* out = (float*)d_out;

    const size_t scat_bytes = (size_t)BATCH * NPRED * sizeof(float4); // 7.68 MB
    const size_t meta_bytes = (size_t)3 * BATCH * NCELL * sizeof(u32);
    if (ws_size >= scat_bytes + meta_bytes) {
        float4* scat  = (float4*)d_ws;
        u32* mstart   = (u32*)((char*)d_ws + scat_bytes);
        u32* mcount   = mstart + BATCH * NCELL;
        u32* cur      = mcount + BATCH * NCELL;
        const int wide = (NPTS + 255) / 256;                 // 1875 blocks
        zero_meta<<<(BATCH * NCELL + 255) / 256, 256, 0, stream>>>(mcount);
        hist<<<wide, 256, 0, stream>>>(pred, mcount);
        prefix<<<BATCH, 512, 0, stream>>>(mcount, mstart, cur);
        scatter<<<wide, 256, 0, stream>>>(pred, cur, scat);
        atss_search<<<BATCH * NGT, 64, 0, stream>>>(
            scat, mstart, mcount, pred, gtb, out);
    } else {
        atss_fullscan<<<BATCH * NGT, 64, 0, stream>>>(pred, gtb, out);
    }
}

// Round 9
// 94.654 us; speedup vs baseline: 1.3121x; 1.3121x over previous
//
#include <hip/hip_runtime.h>
#include <stdint.h>

typedef unsigned long long u64;
typedef unsigned int u32;

#define KCAND 9
#define BATCH 16
#define NPRED 30000
#define NGT   64
#define TPB   256                  // 4 waves
#define GTA   2                    // GTs per block
#define CAP   128                  // candidate slots per GT (expected ~10)
#define INITKEY 0x7F800000FFFFFFFFULL
#define FINF  __uint_as_float(0x7F800000u)
#define SENT  (~0ULL)

__device__ __forceinline__ float wave_min_f(float v) {
#pragma unroll
    for (int s = 1; s < 64; s <<= 1) v = fminf(v, __shfl_xor(v, s, 64));
    return v;
}
__device__ __forceinline__ u64 wave_min_u64(u64 v) {
#pragma unroll
    for (int s = 1; s < 64; s <<= 1) {
        u64 o = __shfl_xor(v, s, 64);
        v = o < v ? o : v;
    }
    return v;
}

// exact reference-rounded dist^2 (all ordering comes from this, contract off)
#define DIST(GX, GY, PX, PY, D)                                              \
    { float _dx = __fsub_rn(GX, PX), _dy = __fsub_rn(GY, PY);                \
      D = __fadd_rn(__fmul_rn(_dx, _dx), __fmul_rn(_dy, _dy)); }

// Single-launch, workspace-free ATSS.  Block = 2 GTs of one image.
// RULE (from r8 crash vs r0-r5 passes): every wave collective (__ballot,
// __shfl, LDS-atomic collect) executes under UNIFORM control flow — loops
// have uniform trip counts; tails use clamped loads + select masks.
__global__ __launch_bounds__(TPB, 2) void atss2(
    const float* __restrict__ pred,   // [B, N, 4] cxcywh
    const float* __restrict__ gt,     // [B, G, 4] cxcywh
    float* __restrict__ out)          // [4][B*G*K] float32
{
#pragma clang fp contract(off)
    const int tid  = threadIdx.x;
    const int lane = tid & 63;
    const int wv   = tid >> 6;

    // grid = 512: bits[2:0]=xcd(img low3), [7:3]=gt-pair, [8]=img-high.
    // XCD k serves images {k, k+8}: 2 x 480KB pred slabs, L2-resident pass 2.
    const int bi = blockIdx.x;
    const int b  = (bi & 7) + 8 * (bi >> 8);
    const int g0 = ((bi >> 3) & 31) * GTA;

    const float4* gt4 = (const float4*)gt;
    const float4 gA = gt4[b * NGT + g0];
    const float4 gB = gt4[b * NGT + g0 + 1];
    const float aX = gA.x, aY = gA.y;
    const float bX = gB.x, bY = gB.y;

    const float4* p4 = (const float4*)pred + (size_t)b * NPRED;

    __shared__ float tmins[GTA][TPB];   // 2 KB per-thread mins
    __shared__ float tg[GTA];
    __shared__ int   cnt[GTA];
    __shared__ u64   cand[GTA][CAP];    // 2 KB

    if (tid < GTA) cnt[tid] = 0;

    // ================= pass 1: per-thread running min per GT ================
    // uniform trip count: i0 in {0, 512, ..., 29696} (59 iters, all threads).
    // body A index i0+tid <= 29696+255 = 29951 < NPRED: always valid.
    // body B index i0+tid+TPB <= 30207: select-masked.
    float lmA = FINF, lmB = FINF;
    for (int i0 = 0; i0 < NPRED; i0 += 2 * TPB) {
        const int i = i0 + tid;
        float4 q0 = p4[i];
        float d;
        DIST(aX, aY, q0.x, q0.y, d); lmA = fminf(lmA, d);
        DIST(bX, bY, q0.x, q0.y, d); lmB = fminf(lmB, d);
        const int i2 = i + TPB;
        const bool vv = i2 < NPRED;
        float4 q1 = p4[vv ? i2 : 0];
        DIST(aX, aY, q1.x, q1.y, d); lmA = fminf(lmA, vv ? d : FINF);
        DIST(bX, bY, q1.x, q1.y, d); lmB = fminf(lmB, vv ? d : FINF);
    }

    tmins[0][tid] = lmA;
    tmins[1][tid] = lmB;
    __syncthreads();

    // ===== threshold per GT: 9th-smallest of 256 thread-mins (wave c) =======
    // <=8 points have d < d9 => <=8 threads have min < d9 => T >= d9.
    // Equal-removal only loosens T upward -> still valid; >=9 pts have d <= T.
    if (wv < GTA) {
        float a[TPB / 64];
#pragma unroll
        for (int j = 0; j < TPB / 64; ++j) a[j] = tmins[wv][j * 64 + lane];
        float T = FINF;
#pragma unroll
        for (int r = 0; r < KCAND; ++r) {
            float ml = a[0];
#pragma unroll
            for (int j = 1; j < TPB / 64; ++j) ml = fminf(ml, a[j]);
            float m = wave_min_f(ml);
#pragma unroll
            for (int j = 0; j < TPB / 64; ++j) a[j] = (a[j] == m) ? FINF : a[j];
            T = m;
        }
        if (lane == 0) tg[wv] = T;
    }
    __syncthreads();
    const float T0 = tg[0], T1 = tg[1];

    // ================= pass 2: rescan + ballot-collect ======================
    // same uniform i0 loop; h-flags masked by validity; ballots at full wave.
#define COLLECT(H, D, C, IDX)                                                \
    { u64 bm = __ballot(H);                                                  \
      if (bm) {                                                              \
          int ldr = __ffsll(bm) - 1;                                         \
          int base = 0;                                                      \
          if (lane == ldr) base = atomicAdd(&cnt[C], (int)__popcll(bm));     \
          base = __shfl(base, ldr, 64);                                      \
          if (H) {                                                           \
              int slot = base + (int)__popcll(bm & ((1ULL << lane) - 1ULL)); \
              if (slot < CAP)                                                \
                  cand[C][slot] =                                            \
                      ((u64)__float_as_uint(D) << 32) | (unsigned)(IDX);     \
          } } }

    for (int i0 = 0; i0 < NPRED; i0 += 2 * TPB) {
        const int i = i0 + tid;                    // always valid (see pass 1)
        float4 q0 = p4[i];
        float e0, e1;
        DIST(aX, aY, q0.x, q0.y, e0);
        DIST(bX, bY, q0.x, q0.y, e1);
        bool h0 = e0 <= T0, h1 = e1 <= T1;
        if (__ballot(h0 | h1)) {                   // wave-uniform condition
            COLLECT(h0, e0, 0, i)
            COLLECT(h1, e1, 1, i)
        }
        const int i2 = i + TPB;
        const bool vv = i2 < NPRED;
        float4 q1 = p4[vv ? i2 : 0];
        DIST(aX, aY, q1.x, q1.y, e0);
        DIST(bX, bY, q1.x, q1.y, e1);
        h0 = vv && (e0 <= T0);
        h1 = vv && (e1 <= T1);
        if (__ballot(h0 | h1)) {                   // wave-uniform condition
            COLLECT(h0, e0, 0, i2)
            COLLECT(h1, e1, 1, i2)
        }
    }
#undef COLLECT
    __syncthreads();

    // ===== exact top-9 selection + epilogue: wave c -> GT c =================
    if (wv >= GTA) return;
    const int c = wv;
    const float gX = c ? bX : aX;
    const float gY = c ? bY : aY;
    const int n = cnt[c];                       // >=9 guaranteed (T >= d9)

    u64 fin = SENT;
    if (n <= CAP) {
        u64 k0 = (lane < n)      ? cand[c][lane]      : SENT;
        u64 k1 = (lane + 64 < n) ? cand[c][lane + 64] : SENT;
#pragma unroll
        for (int r = 0; r < KCAND; ++r) {
            u64 ml = k0 < k1 ? k0 : k1;
            u64 m = wave_min_u64(ml);
            if (lane == r) fin = m;
            if (k0 == m) k0 = SENT;             // keys unique (idx embedded)
            if (k1 == m) k1 = SENT;
        }
    } else {
        // overflow fallback (statistically never): exact sorted-insert over
        // all points, gated by the valid bound T.  val: sorted lanes 0..8.
        // uniform trip count; invalid lanes carry d = +inf.
        u64 val = INITKEY;
        float Tf = tg[c];
        for (int i0 = 0; i0 < NPRED; i0 += 64) {
            const int i = i0 + lane;
            const bool vv = i < NPRED;
            float4 q = p4[vv ? i : 0];
            float d;
            DIST(gX, gY, q.x, q.y, d);
            if (!vv) d = FINF;
            u64 pend = __ballot(d <= Tf);
            while (pend) {
                const int src = __ffsll(pend) - 1;
                pend &= pend - 1;
                const unsigned kd = __shfl(__float_as_uint(d), src, 64);
                const unsigned ki = (unsigned)(i0 + src);
                const u64 key = ((u64)kd << 32) | ki;
                u64 Tkey = __shfl(val, 8, 64);
                if (key < Tkey) {               // wave-uniform
                    const u64 ltm = __ballot(val < key) & 0x1FFULL;
                    const int pos = __popcll(ltm);
                    const u64 sh = __shfl_up(val, 1, 64);
                    if (lane < KCAND) {
                        if (lane == pos)      val = key;
                        else if (lane > pos)  val = sh;
                    }
                    Tkey = __shfl(val, 8, 64);
                    Tf = fminf(tg[c], __uint_as_float((unsigned)(Tkey >> 32)));
                    pend &= __ballot(d <= Tf);
                }
            }
        }
        fin = val;
    }

    const int g = g0 + c;
    const int w = b * NGT + g;
    const float4 gq = c ? gB : gA;
    const float gcx = gq.x, gcy = gq.y;

    const bool active = (lane < KCAND);
    const unsigned idx = active ? (unsigned)(fin & 0xffffffffu) : 0u;

    float4 pbx = p4[idx];

    float gx1 = gcx - 0.5f * gq.z, gy1 = gcy - 0.5f * gq.w;
    float gx2 = gcx + 0.5f * gq.z, gy2 = gcy + 0.5f * gq.w;
    float kx1 = pbx.x - 0.5f * pbx.z, ky1 = pbx.y - 0.5f * pbx.w;
    float kx2 = pbx.x + 0.5f * pbx.z, ky2 = pbx.y + 0.5f * pbx.w;

    float ltx = fmaxf(gx1, kx1), lty = fmaxf(gy1, ky1);
    float rbx = fminf(gx2, kx2), rby = fminf(gy2, ky2);
    float wvd = fmaxf(rbx - ltx, 0.0f);
    float hvd = fmaxf(rby - lty, 0.0f);
    float inter  = wvd * hvd;
    float area_a = (gx2 - gx1) * (gy2 - gy1);
    float area_b = (kx2 - kx1) * (ky2 - ky1);
    float iou = inter / ((area_a + area_b) - inter);

    float v = active ? iou : 0.0f;
    float s = v;
#pragma unroll
    for (int m = 1; m < 64; m <<= 1) s += __shfl_xor(s, m, 64);
    float mean = s / 9.0f;

    float dev = active ? (iou - mean) : 0.0f;
    float ss = dev * dev;
#pragma unroll
    for (int m = 1; m < 64; m <<= 1) ss += __shfl_xor(ss, m, 64);
    float stdv = sqrtf(ss / 8.0f);    // ddof = 1
    float thr = mean + stdv;

    bool inside = (gx1 <= pbx.x) && (pbx.x <= gx2) &&
                  (gy1 <= pbx.y) && (pbx.y <= gy2);
    bool maskk = (iou >= thr) && inside;

    if (active) {
        const size_t chunk = (size_t)BATCH * NGT * KCAND;   // 9216
        const size_t o = (size_t)w * KCAND + lane;
        out[0 * chunk + o] = maskk ? (float)idx : -1.0f;    // pred_idx
        out[1 * chunk + o] = maskk ? (float)g   : -1.0f;    // gt_idx
        out[2 * chunk + o] = maskk ? 1.0f : 0.0f;           // mask
        out[3 * chunk + o] = iou;                           // ious
    }
}

extern "C" void kernel_launch(void* const* d_in, const int* in_sizes, int n_in,
                              void* d_out, int out_size, void* d_ws, size_t ws_size,
                              hipStream_t stream) {
    const float* pred = (const float*)d_in[0];   // [16, 30000, 4] f32
    const float* gtb  = (const float*)d_in[1];   // [16, 64, 4] f32
    float* out = (float*)d_out;
    (void)d_ws; (void)ws_size;   // workspace untouched (fill is unconditional)

    atss2<<<BATCH * (NGT / GTA), TPB, 0, stream>>>(pred, gtb, out);
}